// Round 4
// baseline (280.850 us; speedup 1.0000x reference)
//
#include <hip/hip_runtime.h>
#include <hip/hip_bf16.h>

#define N_TOK 8192
#define D_IN  1024
#define DK    128
#define NT    256   // number of 32-row q tiles

typedef __attribute__((ext_vector_type(8))) short short8;
typedef __attribute__((ext_vector_type(4))) float f32x4;

static __device__ __forceinline__ unsigned short f2bf(float f) {
    __hip_bfloat16 h = __float2bfloat16(f);
    return __builtin_bit_cast(unsigned short, h);
}

// ---------------- one-time W transpose: W[k][n] f32 -> Wt[n][k] bf16 ----------------
__global__ __launch_bounds__(256) void wtrans_kernel(
    const float* __restrict__ Wq, const float* __restrict__ Wk,
    const float* __restrict__ Wv, unsigned short* __restrict__ Wt)
{
    __shared__ unsigned short T[64][72];
    const int proj = blockIdx.y;
    const float* W = (proj == 0) ? Wq : (proj == 1) ? Wk : Wv;
    unsigned short* out = Wt + (size_t)proj * DK * D_IN;
    const int k0 = (blockIdx.x & 15) * 64, n0 = (blockIdx.x >> 4) * 64;
    const int tid = threadIdx.x;
    #pragma unroll
    for (int i = 0; i < 4; i++) {
        int e = tid + i * 256;
        int r = e >> 4, c4 = e & 15;
        float4 v = *reinterpret_cast<const float4*>(&W[(size_t)(k0 + r) * DK + n0 + c4 * 4]);
        T[c4 * 4 + 0][r] = f2bf(v.x);
        T[c4 * 4 + 1][r] = f2bf(v.y);
        T[c4 * 4 + 2][r] = f2bf(v.z);
        T[c4 * 4 + 3][r] = f2bf(v.w);
    }
    __syncthreads();
    #pragma unroll
    for (int i = 0; i < 4; i++) {
        int e = tid + i * 256;
        int r = e >> 4, c4 = e & 15;
        *reinterpret_cast<ushort4*>(&out[(size_t)(n0 + r) * D_IN + k0 + c4 * 4]) =
            *reinterpret_cast<const ushort4*>(&T[r][c4 * 4]);
    }
}

// ---------------- QKV projection: out = X @ W + b, bf16 outputs ----------------
// BM=64 -> grid (128, 3) = 384 blocks. A staged via LDS; B from bf16 Wt (L2).
__global__ __launch_bounds__(256) void proj_kernel(
    const float* __restrict__ X, const unsigned short* __restrict__ Wt,
    const float* __restrict__ bq, const float* __restrict__ bk,
    const float* __restrict__ bv,
    unsigned short* __restrict__ Qb, unsigned short* __restrict__ Kb,
    unsigned short* __restrict__ Vt)
{
    __shared__ unsigned short As[64][72];

    const int tid  = threadIdx.x;
    const int wid  = tid >> 6, lane = tid & 63;
    const int g    = lane >> 4, r16 = lane & 15;
    const int wm   = wid >> 1, wn = wid & 1;   // wave tile: 32 rows x 64 cols
    const int mb   = blockIdx.x * 64;
    const int proj = blockIdx.y;

    const unsigned short* Wtp = Wt + (size_t)proj * DK * D_IN;
    const float* bias = (proj == 0) ? bq : (proj == 1) ? bk : bv;

    f32x4 acc[2][4] = {};

    for (int k0 = 0; k0 < D_IN; k0 += 64) {
        #pragma unroll
        for (int i = 0; i < 4; i++) {
            int e = tid + i * 256;          // 1024 float4s
            int r = e >> 4, c4 = e & 15;
            const float4 v = *reinterpret_cast<const float4*>(
                &X[(size_t)(mb + r) * D_IN + k0 + c4 * 4]);
            ushort4 h;
            h.x = f2bf(v.x); h.y = f2bf(v.y); h.z = f2bf(v.z); h.w = f2bf(v.w);
            *reinterpret_cast<ushort4*>(&As[r][c4 * 4]) = h;
        }
        __syncthreads();
        #pragma unroll
        for (int kk = 0; kk < 64; kk += 32) {
            short8 af[2], bfr[4];
            #pragma unroll
            for (int mi = 0; mi < 2; mi++)
                af[mi] = *reinterpret_cast<const short8*>(&As[wm * 32 + mi * 16 + r16][kk + g * 8]);
            #pragma unroll
            for (int ni = 0; ni < 4; ni++)
                bfr[ni] = *reinterpret_cast<const short8*>(
                    &Wtp[(size_t)(wn * 64 + ni * 16 + r16) * D_IN + k0 + kk + g * 8]);
            #pragma unroll
            for (int mi = 0; mi < 2; mi++)
                #pragma unroll
                for (int ni = 0; ni < 4; ni++)
                    acc[mi][ni] = __builtin_amdgcn_mfma_f32_16x16x32_bf16(
                        af[mi], bfr[ni], acc[mi][ni], 0, 0, 0);
        }
        __syncthreads();
    }

    if (proj < 2) {
        unsigned short* out = (proj == 0) ? Qb : Kb;
        #pragma unroll
        for (int ni = 0; ni < 4; ni++) {
            int n = wn * 64 + ni * 16 + r16;
            float b = bias[n];
            #pragma unroll
            for (int mi = 0; mi < 2; mi++) {
                #pragma unroll
                for (int e = 0; e < 4; e++) {
                    int m = mb + wm * 32 + mi * 16 + g * 4 + e;
                    out[(size_t)m * DK + n] = f2bf(acc[mi][ni][e] + b);
                }
            }
        }
    } else {
        #pragma unroll
        for (int ni = 0; ni < 4; ni++) {
            int n = wn * 64 + ni * 16 + r16;
            float b = bias[n];
            #pragma unroll
            for (int mi = 0; mi < 2; mi++) {
                int m0 = mb + wm * 32 + mi * 16 + g * 4;
                ushort4 h;
                h.x = f2bf(acc[mi][ni][0] + b);
                h.y = f2bf(acc[mi][ni][1] + b);
                h.z = f2bf(acc[mi][ni][2] + b);
                h.w = f2bf(acc[mi][ni][3] + b);
                *reinterpret_cast<ushort4*>(&Vt[(size_t)n * N_TOK + m0]) = h;
            }
        }
    }
}

// ---------------- causal flash attention: one wave per (q-tile, kv-chunk) -------
// grid = (256, max_chunks), 64 threads. No barriers, no inter-wave merge.
// S^T = mfma(K, Q); PV: O^T = mfma(V^T, P^T). Partial written from registers.
__global__ __launch_bounds__(64, 4) void attn_partial(
    const unsigned short* __restrict__ Qb, const unsigned short* __restrict__ Kb,
    const unsigned short* __restrict__ Vt,
    float* __restrict__ Opart, float* __restrict__ Mpart, float* __restrict__ Lpart,
    float* __restrict__ O, int chunk_tiles, int max_chunks, int direct)
{
    __shared__ unsigned short Pq[32][36];   // P[q][kv], pad 36

    const int t = blockIdx.x;
    const int c = blockIdx.y;
    const int j0 = c * chunk_tiles;
    if (j0 > t) return;
    const int jend = min(j0 + chunk_tiles, t + 1);

    const int lane = threadIdx.x;
    const int g = lane >> 4, r16 = lane & 15;
    const int qbase = t * 32;
    const float scale = 0.08838834764831845f;  // 1/sqrt(128)

    // Q fragments (B-operand): col=q=mi*16+r16, k=d
    short8 qf[2][4];
    #pragma unroll
    for (int mi = 0; mi < 2; mi++)
        #pragma unroll
        for (int kd = 0; kd < 4; kd++)
            qf[mi][kd] = *reinterpret_cast<const short8*>(
                &Qb[(size_t)(qbase + mi * 16 + r16) * DK + kd * 32 + g * 8]);

    f32x4 o_acc[2][8] = {};                  // O^T: [q-frag mi][d-frag df]
    float m_run[2] = {-1e30f, -1e30f}, l_run[2] = {0.f, 0.f};

    for (int j = j0; j < jend; ++j) {
        const int kvb = j * 32;
        // ---- V loads first: independent of everything, overlap QK+softmax ----
        short8 vf[8];
        #pragma unroll
        for (int df = 0; df < 8; df++)
            vf[df] = *reinterpret_cast<const short8*>(
                &Vt[(size_t)(df * 16 + r16) * N_TOK + kvb + g * 8]);
        // ---- S^T = K Q^T ----
        f32x4 st[2][2] = {};                 // [ni=kv frag][mi=q frag]
        #pragma unroll
        for (int kd = 0; kd < 4; kd++) {
            short8 kf[2];
            #pragma unroll
            for (int ni = 0; ni < 2; ni++)
                kf[ni] = *reinterpret_cast<const short8*>(
                    &Kb[(size_t)(kvb + ni * 16 + r16) * DK + kd * 32 + g * 8]);
            #pragma unroll
            for (int ni = 0; ni < 2; ni++)
                #pragma unroll
                for (int mi = 0; mi < 2; mi++)
                    st[ni][mi] = __builtin_amdgcn_mfma_f32_16x16x32_bf16(
                        kf[ni], qf[mi][kd], st[ni][mi], 0, 0, 0);
        }
        // ---- online softmax: per q-column (mi,r16); kv spread over (ni,e,g) ----
        float alpha[2];
        #pragma unroll
        for (int mi = 0; mi < 2; mi++) {
            float s[2][4];
            #pragma unroll
            for (int ni = 0; ni < 2; ni++)
                #pragma unroll
                for (int e = 0; e < 4; e++) {
                    float v = st[ni][mi][e] * scale;
                    if (j == t) {
                        int ql = mi * 16 + r16;
                        int kl = ni * 16 + g * 4 + e;
                        if (kl > ql) v = -1e30f;
                    }
                    s[ni][e] = v;
                }
            float lm = fmaxf(fmaxf(fmaxf(s[0][0], s[0][1]), fmaxf(s[0][2], s[0][3])),
                             fmaxf(fmaxf(s[1][0], s[1][1]), fmaxf(s[1][2], s[1][3])));
            lm = fmaxf(lm, __shfl_xor(lm, 16));
            lm = fmaxf(lm, __shfl_xor(lm, 32));
            float mnew = fmaxf(m_run[mi], lm);
            alpha[mi] = __expf(m_run[mi] - mnew);
            float ps[2][4], ls;
            #pragma unroll
            for (int ni = 0; ni < 2; ni++)
                #pragma unroll
                for (int e = 0; e < 4; e++)
                    ps[ni][e] = __expf(s[ni][e] - mnew);
            ls = ((ps[0][0] + ps[0][1]) + (ps[0][2] + ps[0][3]))
               + ((ps[1][0] + ps[1][1]) + (ps[1][2] + ps[1][3]));
            ls += __shfl_xor(ls, 16);
            ls += __shfl_xor(ls, 32);
            l_run[mi] = l_run[mi] * alpha[mi] + ls;
            m_run[mi] = mnew;
            // pack P[q][kv] into LDS: 8B per (mi,ni)
            #pragma unroll
            for (int ni = 0; ni < 2; ni++) {
                ushort4 pk;
                pk.x = f2bf(ps[ni][0]); pk.y = f2bf(ps[ni][1]);
                pk.z = f2bf(ps[ni][2]); pk.w = f2bf(ps[ni][3]);
                *reinterpret_cast<ushort4*>(&Pq[mi * 16 + r16][ni * 16 + g * 4]) = pk;
            }
        }
        // rescale O^T accumulators (skip when no column max grew)
        if (__any(alpha[0] < 1.f) || __any(alpha[1] < 1.f)) {
            #pragma unroll
            for (int mi = 0; mi < 2; mi++)
                #pragma unroll
                for (int df = 0; df < 8; df++)
                    #pragma unroll
                    for (int e = 0; e < 4; e++)
                        o_acc[mi][df][e] *= alpha[mi];
        }
        // P^T B-fragments: col=q=r16, k=kv=g*8+idx
        short8 pb[2];
        pb[0] = *reinterpret_cast<const short8*>(&Pq[r16][g * 8]);
        pb[1] = *reinterpret_cast<const short8*>(&Pq[16 + r16][g * 8]);
        // ---- O^T += V^T P^T ----
        #pragma unroll
        for (int df = 0; df < 8; df++) {
            o_acc[0][df] = __builtin_amdgcn_mfma_f32_16x16x32_bf16(vf[df], pb[0], o_acc[0][df], 0, 0, 0);
            o_acc[1][df] = __builtin_amdgcn_mfma_f32_16x16x32_bf16(vf[df], pb[1], o_acc[1][df], 0, 0, 0);
        }
    }

    // ---- epilogue: write partial (or final) straight from registers ----
    if (direct) {
        #pragma unroll
        for (int mi = 0; mi < 2; mi++) {
            float inv = 1.0f / l_run[mi];
            #pragma unroll
            for (int df = 0; df < 8; df++) {
                f32x4 r = o_acc[mi][df];
                r[0] *= inv; r[1] *= inv; r[2] *= inv; r[3] *= inv;
                *reinterpret_cast<f32x4*>(
                    &O[(size_t)(qbase + mi * 16 + r16) * DK + df * 16 + g * 4]) = r;
            }
        }
    } else {
        size_t pb0 = ((size_t)t * max_chunks + c) * 32;
        #pragma unroll
        for (int mi = 0; mi < 2; mi++) {
            #pragma unroll
            for (int df = 0; df < 8; df++)
                *reinterpret_cast<f32x4*>(
                    &Opart[(pb0 + mi * 16 + r16) * 128 + df * 16 + g * 4]) = o_acc[mi][df];
            if (g == 0) {
                Mpart[pb0 + mi * 16 + r16] = m_run[mi];
                Lpart[pb0 + mi * 16 + r16] = l_run[mi];
            }
        }
    }
}

// ---------------- merge partials across chunks ----------------
__global__ __launch_bounds__(256) void attn_merge(
    const float* __restrict__ Opart, const float* __restrict__ Mpart,
    const float* __restrict__ Lpart, float* __restrict__ O,
    int chunk_tiles, int max_chunks)
{
    __shared__ float Ms[32], Ls[32], Fs[16][32];
    const int t = blockIdx.x;
    const int nc = t / chunk_tiles + 1;
    const int tid = threadIdx.x;

    if (tid < 32) {
        float M = -1e30f;
        for (int c = 0; c < nc; c++)
            M = fmaxf(M, Mpart[((size_t)t * max_chunks + c) * 32 + tid]);
        float L = 0.f;
        for (int c = 0; c < nc; c++) {
            size_t pb = ((size_t)t * max_chunks + c) * 32 + tid;
            L += __expf(Mpart[pb] - M) * Lpart[pb];
        }
        Ms[tid] = M; Ls[tid] = L;
    }
    __syncthreads();
    for (int cc = tid >> 5; cc < nc; cc += 8) {
        int row = tid & 31;
        Fs[cc][row] = __expf(Mpart[((size_t)t * max_chunks + cc) * 32 + row] - Ms[row]);
    }
    __syncthreads();
    #pragma unroll
    for (int it = 0; it < 4; it++) {
        int idx = tid + it * 256;
        int row = idx >> 5, c4 = idx & 31;
        float4 acc = {0.f, 0.f, 0.f, 0.f};
        for (int c = 0; c < nc; c++) {
            const float4 v = *reinterpret_cast<const float4*>(
                &Opart[(((size_t)t * max_chunks + c) * 32 + row) * 128 + c4 * 4]);
            float f = Fs[c][row];
            acc.x += f * v.x; acc.y += f * v.y; acc.z += f * v.z; acc.w += f * v.w;
        }
        float inv = 1.0f / Ls[row];
        float4 r;
        r.x = acc.x * inv; r.y = acc.y * inv; r.z = acc.z * inv; r.w = acc.w * inv;
        *reinterpret_cast<float4*>(&O[((size_t)t * 32 + row) * DK + c4 * 4]) = r;
    }
}

extern "C" void kernel_launch(void* const* d_in, const int* in_sizes, int n_in,
                              void* d_out, int out_size, void* d_ws, size_t ws_size,
                              hipStream_t stream) {
    const float* X  = (const float*)d_in[0];
    const float* Wq = (const float*)d_in[1];
    const float* bq = (const float*)d_in[2];
    const float* Wk = (const float*)d_in[3];
    const float* bk = (const float*)d_in[4];
    const float* Wv = (const float*)d_in[5];
    const float* bv = (const float*)d_in[6];
    float* O = (float*)d_out;

    unsigned short* Qb = (unsigned short*)d_ws;
    unsigned short* Kb = Qb + (size_t)N_TOK * DK;
    unsigned short* Vt = Kb + (size_t)N_TOK * DK;
    unsigned short* Wt = Vt + (size_t)N_TOK * DK;
    float* Opart = (float*)(Wt + (size_t)3 * DK * D_IN);
    size_t base_bytes = (size_t)((char*)Opart - (char*)d_ws);

    int chunk_tiles = 0, max_chunks = 1, direct = 0;
    const int opts[4] = {16, 32, 64, 128};
    for (int i = 0; i < 4; i++) {
        int ct = opts[i], mc = NT / ct;
        size_t need = base_bytes + (size_t)NT * mc * 32 * (128 + 2) * sizeof(float);
        if (need <= ws_size) { chunk_tiles = ct; max_chunks = mc; break; }
    }
    if (!chunk_tiles) { chunk_tiles = NT; max_chunks = 1; direct = 1; }
    float* Mpart = Opart + (size_t)NT * max_chunks * 32 * 128;
    float* Lpart = Mpart + (size_t)NT * max_chunks * 32;

    wtrans_kernel<<<dim3(32, 3), 256, 0, stream>>>(Wq, Wk, Wv, Wt);
    proj_kernel<<<dim3(128, 3), 256, 0, stream>>>(X, Wt, bq, bk, bv, Qb, Kb, Vt);
    attn_partial<<<dim3(NT, max_chunks), 64, 0, stream>>>(
        Qb, Kb, Vt, Opart, Mpart, Lpart, O, chunk_tiles, max_chunks, direct);
    if (!direct)
        attn_merge<<<dim3(NT), 256, 0, stream>>>(Opart, Mpart, Lpart, O,
                                                 chunk_tiles, max_chunks);
}

// Round 5
// 116.696 us; speedup vs baseline: 2.4067x; 2.4067x over previous
//
#include <hip/hip_runtime.h>
#include <hip/hip_bf16.h>

#define N_TOK 8192
#define D_IN  1024
#define DK    128
#define NT    256   // number of 32-row q tiles

typedef __attribute__((ext_vector_type(8))) short short8;
typedef __attribute__((ext_vector_type(4))) float f32x4;

static __device__ __forceinline__ unsigned short f2bf(float f) {
    __hip_bfloat16 h = __float2bfloat16(f);
    return __builtin_bit_cast(unsigned short, h);
}

static __device__ __forceinline__ void gl_lds16(const void* g, void* l) {
    __builtin_amdgcn_global_load_lds(
        (const __attribute__((address_space(1))) void*)g,
        (__attribute__((address_space(3))) void*)l, 16, 0, 0);
}

// ---------------- one-time W transpose: W[k][n] f32 -> Wt[n][k] bf16 ----------------
__global__ __launch_bounds__(256) void wtrans_kernel(
    const float* __restrict__ Wq, const float* __restrict__ Wk,
    const float* __restrict__ Wv, unsigned short* __restrict__ Wt)
{
    __shared__ unsigned short T[64][72];
    const int proj = blockIdx.y;
    const float* W = (proj == 0) ? Wq : (proj == 1) ? Wk : Wv;
    unsigned short* out = Wt + (size_t)proj * DK * D_IN;
    const int k0 = (blockIdx.x & 15) * 64, n0 = (blockIdx.x >> 4) * 64;
    const int tid = threadIdx.x;
    #pragma unroll
    for (int i = 0; i < 4; i++) {
        int e = tid + i * 256;
        int r = e >> 4, c4 = e & 15;
        float4 v = *reinterpret_cast<const float4*>(&W[(size_t)(k0 + r) * DK + n0 + c4 * 4]);
        T[c4 * 4 + 0][r] = f2bf(v.x);
        T[c4 * 4 + 1][r] = f2bf(v.y);
        T[c4 * 4 + 2][r] = f2bf(v.z);
        T[c4 * 4 + 3][r] = f2bf(v.w);
    }
    __syncthreads();
    #pragma unroll
    for (int i = 0; i < 4; i++) {
        int e = tid + i * 256;
        int r = e >> 4, c4 = e & 15;
        *reinterpret_cast<ushort4*>(&out[(size_t)(n0 + r) * D_IN + k0 + c4 * 4]) =
            *reinterpret_cast<const ushort4*>(&T[r][c4 * 4]);
    }
}

// ---------------- QKV projection: out = X @ W + b, bf16 outputs ----------------
// Q plain row-major. K row-major with 16B-block XOR swizzle within each row
// (block' = block ^ (kv&7)) so attn can global_load_lds linearly and
// ds_read conflict-free. V transposed [d][kv] with block' = block ^ (d&3)
// within 32-kv groups.
__global__ __launch_bounds__(256) void proj_kernel(
    const float* __restrict__ X, const unsigned short* __restrict__ Wt,
    const float* __restrict__ bq, const float* __restrict__ bk,
    const float* __restrict__ bv,
    unsigned short* __restrict__ Qb, unsigned short* __restrict__ Kb,
    unsigned short* __restrict__ Vt)
{
    __shared__ unsigned short As[64][72];

    const int tid  = threadIdx.x;
    const int wid  = tid >> 6, lane = tid & 63;
    const int g    = lane >> 4, r16 = lane & 15;
    const int wm   = wid >> 1, wn = wid & 1;   // wave tile: 32 rows x 64 cols
    const int mb   = blockIdx.x * 64;
    const int proj = blockIdx.y;

    const unsigned short* Wtp = Wt + (size_t)proj * DK * D_IN;
    const float* bias = (proj == 0) ? bq : (proj == 1) ? bk : bv;

    f32x4 acc[2][4] = {};

    for (int k0 = 0; k0 < D_IN; k0 += 64) {
        #pragma unroll
        for (int i = 0; i < 4; i++) {
            int e = tid + i * 256;          // 1024 float4s
            int r = e >> 4, c4 = e & 15;
            const float4 v = *reinterpret_cast<const float4*>(
                &X[(size_t)(mb + r) * D_IN + k0 + c4 * 4]);
            ushort4 h;
            h.x = f2bf(v.x); h.y = f2bf(v.y); h.z = f2bf(v.z); h.w = f2bf(v.w);
            *reinterpret_cast<ushort4*>(&As[r][c4 * 4]) = h;
        }
        __syncthreads();
        #pragma unroll
        for (int kk = 0; kk < 64; kk += 32) {
            short8 af[2], bfr[4];
            #pragma unroll
            for (int mi = 0; mi < 2; mi++)
                af[mi] = *reinterpret_cast<const short8*>(&As[wm * 32 + mi * 16 + r16][kk + g * 8]);
            #pragma unroll
            for (int ni = 0; ni < 4; ni++)
                bfr[ni] = *reinterpret_cast<const short8*>(
                    &Wtp[(size_t)(wn * 64 + ni * 16 + r16) * D_IN + k0 + kk + g * 8]);
            #pragma unroll
            for (int mi = 0; mi < 2; mi++)
                #pragma unroll
                for (int ni = 0; ni < 4; ni++)
                    acc[mi][ni] = __builtin_amdgcn_mfma_f32_16x16x32_bf16(
                        af[mi], bfr[ni], acc[mi][ni], 0, 0, 0);
        }
        __syncthreads();
    }

    if (proj < 2) {
        unsigned short* out = (proj == 0) ? Qb : Kb;
        #pragma unroll
        for (int ni = 0; ni < 4; ni++) {
            int n = wn * 64 + ni * 16 + r16;
            float b = bias[n];
            #pragma unroll
            for (int mi = 0; mi < 2; mi++) {
                #pragma unroll
                for (int e = 0; e < 4; e++) {
                    int m = mb + wm * 32 + mi * 16 + g * 4 + e;
                    int nc = n;
                    if (proj == 1)   // K swizzle: 16B block ^= (kv&7)
                        nc = ((((n >> 3) ^ (m & 7)) << 3) | (n & 7));
                    out[(size_t)m * DK + nc] = f2bf(acc[mi][ni][e] + b);
                }
            }
        }
    } else {
        #pragma unroll
        for (int ni = 0; ni < 4; ni++) {
            int n = wn * 64 + ni * 16 + r16;
            float b = bias[n];
            #pragma unroll
            for (int mi = 0; mi < 2; mi++) {
                int m0 = mb + wm * 32 + mi * 16 + g * 4;
                // V swizzle within 32-kv group: block' = ((m&31)>>3) ^ (n&3)
                int mblk = (((m0 & 31) >> 3) ^ (n & 3));
                int mp = (m0 & ~31) | (mblk << 3) | (m0 & 7);
                ushort4 h;
                h.x = f2bf(acc[mi][ni][0] + b);
                h.y = f2bf(acc[mi][ni][1] + b);
                h.z = f2bf(acc[mi][ni][2] + b);
                h.w = f2bf(acc[mi][ni][3] + b);
                *reinterpret_cast<ushort4*>(&Vt[(size_t)n * N_TOK + mp]) = h;
            }
        }
    }
}

// ---------------- causal flash attention, LDS-staged K/V, 2-phase pipeline ------
// grid = (64 q-blocks, max_chunks). Block (qb,c): q rows [qb*128, +128),
// kv tiles [c*ct, min((c+1)*ct, 4qb+4)). 4 waves each own 32 q rows and share
// the LDS K/V tiles. Double-buffered staging via global_load_lds (pre-swizzled
// global K/V). Swapped QK^T, in-register softmax in exp2 domain.
__global__ __launch_bounds__(256, 3) void attn_partial(
    const unsigned short* __restrict__ Qb, const unsigned short* __restrict__ Ksw,
    const unsigned short* __restrict__ Vsw,
    float* __restrict__ Opart, float* __restrict__ Mpart, float* __restrict__ Lpart,
    float* __restrict__ O, int chunk_tiles, int max_chunks, int direct)
{
    __shared__ unsigned short Klds[2][32][128];   // 16 KB
    __shared__ unsigned short Vlds[2][128][32];   // 16 KB
    __shared__ unsigned short Pq[4][32][36];      // 9.2 KB, per-wave P[q][kv]

    const int qb = blockIdx.x, c = blockIdx.y;
    const int j0 = c * chunk_tiles;
    const int jmax = 4 * qb + 4;
    const int jend = min(j0 + chunk_tiles, jmax);
    if (j0 >= jend) return;
    const int nt = jend - j0;

    const int tid = threadIdx.x;
    const int wid = tid >> 6, lane = tid & 63;
    const int g = lane >> 4, r16 = lane & 15;
    const int t = qb * 4 + wid;     // this wave's 32-row q tile index
    const int qw = t * 32;          // global q base of this wave
    const float scale2 = 0.08838834764831845f * 1.4426950408889634f; // /sqrt(dk)*log2e

    auto STAGE = [&](int buf, int kvb) {
        #pragma unroll
        for (int s = 0; s < 2; s++) {                  // K: 8KB linear copy
            int ob = ((wid * 2 + s) << 10);
            gl_lds16((const char*)Ksw + ((size_t)kvb << 8) + ob + (lane << 4),
                     (char*)&Klds[buf][0][0] + ob);
        }
        #pragma unroll
        for (int s = 0; s < 2; s++) {                  // V: 128 rows x 64B
            int ob = ((wid * 2 + s) << 10);
            int o = ob + (lane << 4);
            int d = o >> 6, cb = o & 63;
            gl_lds16((const char*)Vsw + (((size_t)d * N_TOK + kvb) << 1) + cb,
                     (char*)&Vlds[buf][0][0] + ob);
        }
    };

    // Q fragments (B-operand): col=q=mi*16+r16, k=d
    short8 qf[2][4];
    #pragma unroll
    for (int mi = 0; mi < 2; mi++)
        #pragma unroll
        for (int kd = 0; kd < 4; kd++)
            qf[mi][kd] = *reinterpret_cast<const short8*>(
                &Qb[(size_t)(qw + mi * 16 + r16) * DK + kd * 32 + g * 8]);

    f32x4 o_acc[2][8] = {};                  // O^T: [q-frag mi][d-frag df]
    float m_run[2] = {-1e30f, -1e30f}, l_run[2] = {0.f, 0.f};

    STAGE(0, j0 * 32);
    __syncthreads();

    int cur = 0;
    for (int it = 0; it < nt; ++it) {
        const int kvb = (j0 + it) * 32;
        if (it + 1 < nt) STAGE(cur ^ 1, kvb + 32);

        const unsigned short* Kl = &Klds[cur][0][0];
        const unsigned short* Vl = &Vlds[cur][0][0];

        // ---- S^T = K Q^T from LDS (swizzled reads) ----
        f32x4 st[2][2] = {};                 // [ni=kv frag][mi=q frag]
        #pragma unroll
        for (int kd = 0; kd < 4; kd++) {
            int swb = ((((kd << 2) | g) ^ (r16 & 7)) << 3);
            short8 kf0 = *reinterpret_cast<const short8*>(Kl + r16 * 128 + swb);
            short8 kf1 = *reinterpret_cast<const short8*>(Kl + (16 + r16) * 128 + swb);
            st[0][0] = __builtin_amdgcn_mfma_f32_16x16x32_bf16(kf0, qf[0][kd], st[0][0], 0, 0, 0);
            st[0][1] = __builtin_amdgcn_mfma_f32_16x16x32_bf16(kf0, qf[1][kd], st[0][1], 0, 0, 0);
            st[1][0] = __builtin_amdgcn_mfma_f32_16x16x32_bf16(kf1, qf[0][kd], st[1][0], 0, 0, 0);
            st[1][1] = __builtin_amdgcn_mfma_f32_16x16x32_bf16(kf1, qf[1][kd], st[1][1], 0, 0, 0);
        }

        // ---- online softmax (exp2 domain), per q-column (mi,r16) ----
        const bool anymask = (kvb + 31 > qw);
        float alpha[2];
        #pragma unroll
        for (int mi = 0; mi < 2; mi++) {
            const int qrow = qw + mi * 16 + r16;
            float s[2][4];
            #pragma unroll
            for (int ni = 0; ni < 2; ni++)
                #pragma unroll
                for (int e = 0; e < 4; e++) {
                    float v = st[ni][mi][e] * scale2;
                    if (anymask && (kvb + ni * 16 + g * 4 + e > qrow)) v = -1e30f;
                    s[ni][e] = v;
                }
            float lm = fmaxf(fmaxf(fmaxf(s[0][0], s[0][1]), fmaxf(s[0][2], s[0][3])),
                             fmaxf(fmaxf(s[1][0], s[1][1]), fmaxf(s[1][2], s[1][3])));
            lm = fmaxf(lm, __shfl_xor(lm, 16));
            lm = fmaxf(lm, __shfl_xor(lm, 32));
            float mnew = fmaxf(m_run[mi], lm);
            alpha[mi] = exp2f(m_run[mi] - mnew);
            float ps[2][4], ls;
            #pragma unroll
            for (int ni = 0; ni < 2; ni++)
                #pragma unroll
                for (int e = 0; e < 4; e++)
                    ps[ni][e] = exp2f(s[ni][e] - mnew);
            ls = ((ps[0][0] + ps[0][1]) + (ps[0][2] + ps[0][3]))
               + ((ps[1][0] + ps[1][1]) + (ps[1][2] + ps[1][3]));
            ls += __shfl_xor(ls, 16);
            ls += __shfl_xor(ls, 32);
            l_run[mi] = l_run[mi] * alpha[mi] + ls;
            m_run[mi] = mnew;
            #pragma unroll
            for (int ni = 0; ni < 2; ni++) {
                ushort4 pk;
                pk.x = f2bf(ps[ni][0]); pk.y = f2bf(ps[ni][1]);
                pk.z = f2bf(ps[ni][2]); pk.w = f2bf(ps[ni][3]);
                *reinterpret_cast<ushort4*>(&Pq[wid][mi * 16 + r16][ni * 16 + g * 4]) = pk;
            }
        }
        if (__any(alpha[0] < 1.f) || __any(alpha[1] < 1.f)) {
            #pragma unroll
            for (int mi = 0; mi < 2; mi++)
                #pragma unroll
                for (int df = 0; df < 8; df++)
                    #pragma unroll
                    for (int e = 0; e < 4; e++)
                        o_acc[mi][df][e] *= alpha[mi];
        }
        // P^T B-fragments: col=q=r16, k=kv=g*8+idx
        short8 pb0 = *reinterpret_cast<const short8*>(&Pq[wid][r16][g * 8]);
        short8 pb1 = *reinterpret_cast<const short8*>(&Pq[wid][16 + r16][g * 8]);
        // ---- O^T += V^T P^T, V from LDS (swizzled reads) ----
        const int swv = ((g ^ (r16 & 3)) << 3);
        #pragma unroll
        for (int df = 0; df < 8; df++) {
            short8 vf = *reinterpret_cast<const short8*>(Vl + (df * 16 + r16) * 32 + swv);
            o_acc[0][df] = __builtin_amdgcn_mfma_f32_16x16x32_bf16(vf, pb0, o_acc[0][df], 0, 0, 0);
            o_acc[1][df] = __builtin_amdgcn_mfma_f32_16x16x32_bf16(vf, pb1, o_acc[1][df], 0, 0, 0);
        }

        __syncthreads();   // drains vmcnt (stage done) + protects both dbuf dirs
        cur ^= 1;
    }

    // ---- epilogue: write partial (or final) straight from registers ----
    if (direct) {
        #pragma unroll
        for (int mi = 0; mi < 2; mi++) {
            float inv = 1.0f / l_run[mi];
            #pragma unroll
            for (int df = 0; df < 8; df++) {
                f32x4 r = o_acc[mi][df];
                r[0] *= inv; r[1] *= inv; r[2] *= inv; r[3] *= inv;
                *reinterpret_cast<f32x4*>(
                    &O[(size_t)(qw + mi * 16 + r16) * DK + df * 16 + g * 4]) = r;
            }
        }
    } else {
        size_t pb0i = ((size_t)t * max_chunks + c) * 32;
        #pragma unroll
        for (int mi = 0; mi < 2; mi++) {
            #pragma unroll
            for (int df = 0; df < 8; df++)
                *reinterpret_cast<f32x4*>(
                    &Opart[(pb0i + mi * 16 + r16) * 128 + df * 16 + g * 4]) = o_acc[mi][df];
            if (g == 0) {
                Mpart[pb0i + mi * 16 + r16] = m_run[mi];
                Lpart[pb0i + mi * 16 + r16] = l_run[mi];
            }
        }
    }
}

// ---------------- merge partials across chunks (exp2 domain) ----------------
__global__ __launch_bounds__(256) void attn_merge(
    const float* __restrict__ Opart, const float* __restrict__ Mpart,
    const float* __restrict__ Lpart, float* __restrict__ O,
    int chunk_tiles, int max_chunks)
{
    __shared__ float Ms[32], Ls[32], Fs[16][32];
    const int t = blockIdx.x;
    const int nc = t / chunk_tiles + 1;
    const int tid = threadIdx.x;

    if (tid < 32) {
        float M = -1e30f;
        for (int c = 0; c < nc; c++)
            M = fmaxf(M, Mpart[((size_t)t * max_chunks + c) * 32 + tid]);
        float L = 0.f;
        for (int c = 0; c < nc; c++) {
            size_t pb = ((size_t)t * max_chunks + c) * 32 + tid;
            L += exp2f(Mpart[pb] - M) * Lpart[pb];
        }
        Ms[tid] = M; Ls[tid] = L;
    }
    __syncthreads();
    for (int cc = tid >> 5; cc < nc; cc += 8) {
        int row = tid & 31;
        Fs[cc][row] = exp2f(Mpart[((size_t)t * max_chunks + cc) * 32 + row] - Ms[row]);
    }
    __syncthreads();
    #pragma unroll
    for (int it = 0; it < 4; it++) {
        int idx = tid + it * 256;
        int row = idx >> 5, c4 = idx & 31;
        float4 acc = {0.f, 0.f, 0.f, 0.f};
        for (int c = 0; c < nc; c++) {
            const float4 v = *reinterpret_cast<const float4*>(
                &Opart[(((size_t)t * max_chunks + c) * 32 + row) * 128 + c4 * 4]);
            float f = Fs[c][row];
            acc.x += f * v.x; acc.y += f * v.y; acc.z += f * v.z; acc.w += f * v.w;
        }
        float inv = 1.0f / Ls[row];
        float4 r;
        r.x = acc.x * inv; r.y = acc.y * inv; r.z = acc.z * inv; r.w = acc.w * inv;
        *reinterpret_cast<float4*>(&O[((size_t)t * 32 + row) * DK + c4 * 4]) = r;
    }
}

extern "C" void kernel_launch(void* const* d_in, const int* in_sizes, int n_in,
                              void* d_out, int out_size, void* d_ws, size_t ws_size,
                              hipStream_t stream) {
    const float* X  = (const float*)d_in[0];
    const float* Wq = (const float*)d_in[1];
    const float* bq = (const float*)d_in[2];
    const float* Wk = (const float*)d_in[3];
    const float* bk = (const float*)d_in[4];
    const float* Wv = (const float*)d_in[5];
    const float* bv = (const float*)d_in[6];
    float* O = (float*)d_out;

    unsigned short* Qb = (unsigned short*)d_ws;
    unsigned short* Kb = Qb + (size_t)N_TOK * DK;
    unsigned short* Vt = Kb + (size_t)N_TOK * DK;
    unsigned short* Wt = Vt + (size_t)N_TOK * DK;
    float* Opart = (float*)(Wt + (size_t)3 * DK * D_IN);
    size_t base_bytes = (size_t)((char*)Opart - (char*)d_ws);

    int chunk_tiles = 0, max_chunks = 1, direct = 0;
    const int opts[4] = {16, 32, 64, 128};
    for (int i = 0; i < 4; i++) {
        int ct = opts[i], mc = NT / ct;
        size_t need = base_bytes + (size_t)NT * mc * 32 * (128 + 2) * sizeof(float);
        if (need <= ws_size) { chunk_tiles = ct; max_chunks = mc; break; }
    }
    if (!chunk_tiles) { chunk_tiles = NT; max_chunks = 1; direct = 1; }
    float* Mpart = Opart + (size_t)NT * max_chunks * 32 * 128;
    float* Lpart = Mpart + (size_t)NT * max_chunks * 32;

    wtrans_kernel<<<dim3(32, 3), 256, 0, stream>>>(Wq, Wk, Wv, Wt);
    proj_kernel<<<dim3(128, 3), 256, 0, stream>>>(X, Wt, bq, bk, bv, Qb, Kb, Vt);
    int grid_c = direct ? 1 : max_chunks;
    attn_partial<<<dim3(64, grid_c), 256, 0, stream>>>(
        Qb, Kb, Vt, Opart, Mpart, Lpart, O, chunk_tiles, max_chunks, direct);
    if (!direct)
        attn_merge<<<dim3(NT), 256, 0, stream>>>(Opart, Mpart, Lpart, O,
                                                 chunk_tiles, max_chunks);
}

// Round 6
// 112.376 us; speedup vs baseline: 2.4992x; 1.0384x over previous
//
#include <hip/hip_runtime.h>
#include <hip/hip_bf16.h>

#define N_TOK 8192
#define D_IN  1024
#define DK    128
#define NT    256   // number of 32-row q tiles

typedef __attribute__((ext_vector_type(8))) short short8;
typedef __attribute__((ext_vector_type(4))) float f32x4;

static __device__ __forceinline__ unsigned short f2bf(float f) {
    __hip_bfloat16 h = __float2bfloat16(f);
    return __builtin_bit_cast(unsigned short, h);
}

static __device__ __forceinline__ void gl_lds16(const void* g, void* l) {
    __builtin_amdgcn_global_load_lds(
        (const __attribute__((address_space(1))) void*)g,
        (__attribute__((address_space(3))) void*)l, 16, 0, 0);
}

// ---------------- one-time W transpose: W[k][n] f32 -> Wt[n][k] bf16 ----------------
__global__ __launch_bounds__(256) void wtrans_kernel(
    const float* __restrict__ Wq, const float* __restrict__ Wk,
    const float* __restrict__ Wv, unsigned short* __restrict__ Wt)
{
    __shared__ unsigned short T[64][72];
    const int proj = blockIdx.y;
    const float* W = (proj == 0) ? Wq : (proj == 1) ? Wk : Wv;
    unsigned short* out = Wt + (size_t)proj * DK * D_IN;
    const int k0 = (blockIdx.x & 15) * 64, n0 = (blockIdx.x >> 4) * 64;
    const int tid = threadIdx.x;
    #pragma unroll
    for (int i = 0; i < 4; i++) {
        int e = tid + i * 256;
        int r = e >> 4, c4 = e & 15;
        float4 v = *reinterpret_cast<const float4*>(&W[(size_t)(k0 + r) * DK + n0 + c4 * 4]);
        T[c4 * 4 + 0][r] = f2bf(v.x);
        T[c4 * 4 + 1][r] = f2bf(v.y);
        T[c4 * 4 + 2][r] = f2bf(v.z);
        T[c4 * 4 + 3][r] = f2bf(v.w);
    }
    __syncthreads();
    #pragma unroll
    for (int i = 0; i < 4; i++) {
        int e = tid + i * 256;
        int r = e >> 4, c4 = e & 15;
        *reinterpret_cast<ushort4*>(&out[(size_t)(n0 + r) * D_IN + k0 + c4 * 4]) =
            *reinterpret_cast<const ushort4*>(&T[r][c4 * 4]);
    }
}

// ---------------- fused QKV projection: reads X ONCE ----------------
// grid = 256 blocks, BM=32. 4 waves split the 384 output cols (96 each).
// X reg-staged f32->bf16 into double-buffered LDS (loads issued before
// compute, written after). W fragments read directly from bf16 Wt (L2).
// Q row-major; K row-major 16B-block-swizzled; V transposed+swizzled.
__global__ __launch_bounds__(256) void proj_fused(
    const float* __restrict__ X, const unsigned short* __restrict__ Wt,
    const float* __restrict__ bq, const float* __restrict__ bk,
    const float* __restrict__ bv,
    unsigned short* __restrict__ Qb, unsigned short* __restrict__ Kb,
    unsigned short* __restrict__ Vt)
{
    __shared__ unsigned short Xs[2][32][72];   // 32 rows x 64 k bf16, pad 72

    const int tid = threadIdx.x;
    const int wid = tid >> 6, lane = tid & 63;
    const int g = lane >> 4, r16 = lane & 15;
    const int mb = blockIdx.x * 32;

    float4 xr[2];
    auto XLOAD = [&](int k0) {
        #pragma unroll
        for (int i = 0; i < 2; i++) {
            int e = tid + i * 256;      // 512 float4s = 32x64 f32
            int r = e >> 4, c4 = e & 15;
            xr[i] = *reinterpret_cast<const float4*>(
                &X[(size_t)(mb + r) * D_IN + k0 + c4 * 4]);
        }
    };
    auto XWRITE = [&](int buf) {
        #pragma unroll
        for (int i = 0; i < 2; i++) {
            int e = tid + i * 256;
            int r = e >> 4, c4 = e & 15;
            ushort4 h;
            h.x = f2bf(xr[i].x); h.y = f2bf(xr[i].y);
            h.z = f2bf(xr[i].z); h.w = f2bf(xr[i].w);
            *reinterpret_cast<ushort4*>(&Xs[buf][r][c4 * 4]) = h;
        }
    };

    f32x4 acc[2][6] = {};   // [mi: 16-row frag][ni: 16-col frag], wave cols [96w,96w+96)

    XLOAD(0); XWRITE(0);
    __syncthreads();
    for (int s = 0; s < 16; ++s) {
        const int k0 = s * 64;
        const int cur = s & 1;
        if (s + 1 < 16) XLOAD(k0 + 64);
        #pragma unroll
        for (int kk = 0; kk < 64; kk += 32) {
            short8 af[2], bfr[6];
            #pragma unroll
            for (int mi = 0; mi < 2; mi++)
                af[mi] = *reinterpret_cast<const short8*>(&Xs[cur][mi * 16 + r16][kk + g * 8]);
            #pragma unroll
            for (int ni = 0; ni < 6; ni++) {
                int nn = wid * 96 + ni * 16;       // global col-block base
                int pj = nn >> 7;
                bfr[ni] = *reinterpret_cast<const short8*>(
                    &Wt[((size_t)pj * DK + (nn & 127) + r16) * D_IN + k0 + kk + g * 8]);
            }
            __builtin_amdgcn_s_setprio(1);
            #pragma unroll
            for (int mi = 0; mi < 2; mi++)
                #pragma unroll
                for (int ni = 0; ni < 6; ni++)
                    acc[mi][ni] = __builtin_amdgcn_mfma_f32_16x16x32_bf16(
                        af[mi], bfr[ni], acc[mi][ni], 0, 0, 0);
            __builtin_amdgcn_s_setprio(0);
        }
        if (s + 1 < 16) XWRITE((s + 1) & 1);   // other buffer: no race with readers
        __syncthreads();
    }

    // ---- epilogue ----
    #pragma unroll
    for (int ni = 0; ni < 6; ni++) {
        int nn = wid * 96 + ni * 16;
        int pj = nn >> 7;
        int n = (nn & 127) + r16;
        const float* bias = (pj == 0) ? bq : (pj == 1) ? bk : bv;
        float b = bias[n];
        if (pj < 2) {
            unsigned short* out = (pj == 0) ? Qb : Kb;
            #pragma unroll
            for (int mi = 0; mi < 2; mi++)
                #pragma unroll
                for (int e = 0; e < 4; e++) {
                    int m = mb + mi * 16 + g * 4 + e;
                    int nc = n;
                    if (pj == 1)   // K swizzle: 16B block ^= (kv&7)
                        nc = ((((n >> 3) ^ (m & 7)) << 3) | (n & 7));
                    out[(size_t)m * DK + nc] = f2bf(acc[mi][ni][e] + b);
                }
        } else {
            #pragma unroll
            for (int mi = 0; mi < 2; mi++) {
                int m0 = mb + mi * 16 + g * 4;
                int mblk = (((m0 & 31) >> 3) ^ (n & 3));
                int mp = (m0 & ~31) | (mblk << 3) | (m0 & 7);
                ushort4 h;
                h.x = f2bf(acc[mi][ni][0] + b);
                h.y = f2bf(acc[mi][ni][1] + b);
                h.z = f2bf(acc[mi][ni][2] + b);
                h.w = f2bf(acc[mi][ni][3] + b);
                *reinterpret_cast<ushort4*>(&Vt[(size_t)n * N_TOK + mp]) = h;
            }
        }
    }
}

// ---------------- causal flash attention, LDS-staged K/V, counted-vmcnt pipeline --
// grid = (64 q-blocks, max_chunks). Block (qb,c): q rows [qb*128,+128), kv tiles
// [c*ct, min((c+1)*ct, 4qb+4)). 4 waves each own 32 q rows, share LDS K/V.
// Double-buffered global_load_lds with s_waitcnt vmcnt(4): next tile's loads
// stay in flight across the raw s_barrier (T3/T4).
__global__ __launch_bounds__(256, 3) void attn_partial(
    const unsigned short* __restrict__ Qb, const unsigned short* __restrict__ Ksw,
    const unsigned short* __restrict__ Vsw,
    float* __restrict__ Opart, float* __restrict__ Mpart, float* __restrict__ Lpart,
    float* __restrict__ O, int chunk_tiles, int max_chunks, int direct)
{
    __shared__ unsigned short Klds[2][32][128];   // 16 KB
    __shared__ unsigned short Vlds[2][128][32];   // 16 KB
    __shared__ unsigned short Pq[4][32][36];      // 9.2 KB, per-wave P[q][kv]

    const int qb = blockIdx.x, c = blockIdx.y;
    const int j0 = c * chunk_tiles;
    const int jmax = 4 * qb + 4;
    const int jend = min(j0 + chunk_tiles, jmax);
    if (j0 >= jend) return;
    const int nt = jend - j0;

    const int tid = threadIdx.x;
    const int wid = tid >> 6, lane = tid & 63;
    const int g = lane >> 4, r16 = lane & 15;
    const int t = qb * 4 + wid;     // this wave's 32-row q tile index
    const int qw = t * 32;          // global q base of this wave
    const float scale2 = 0.08838834764831845f * 1.4426950408889634f; // /sqrt(dk)*log2e

    auto STAGE = [&](int buf, int kvb) {   // exactly 4 gl_lds per thread
        #pragma unroll
        for (int s = 0; s < 2; s++) {                  // K: 8KB linear copy
            int ob = ((wid * 2 + s) << 10);
            gl_lds16((const char*)Ksw + ((size_t)kvb << 8) + ob + (lane << 4),
                     (char*)&Klds[buf][0][0] + ob);
        }
        #pragma unroll
        for (int s = 0; s < 2; s++) {                  // V: 128 rows x 64B
            int ob = ((wid * 2 + s) << 10);
            int o = ob + (lane << 4);
            int d = o >> 6, cb = o & 63;
            gl_lds16((const char*)Vsw + (((size_t)d * N_TOK + kvb) << 1) + cb,
                     (char*)&Vlds[buf][0][0] + ob);
        }
    };

    // Q fragments (B-operand): col=q=mi*16+r16, k=d
    short8 qf[2][4];
    #pragma unroll
    for (int mi = 0; mi < 2; mi++)
        #pragma unroll
        for (int kd = 0; kd < 4; kd++)
            qf[mi][kd] = *reinterpret_cast<const short8*>(
                &Qb[(size_t)(qw + mi * 16 + r16) * DK + kd * 32 + g * 8]);

    f32x4 o_acc[2][8] = {};                  // O^T: [q-frag mi][d-frag df]
    float m_run[2] = {-1e30f, -1e30f}, l_run[2] = {0.f, 0.f};

    STAGE(0, j0 * 32);

    int cur = 0;
    for (int it = 0; it < nt; ++it) {
        const int kvb = (j0 + it) * 32;
        if (it + 1 < nt) {
            STAGE(cur ^ 1, kvb + 32);
            asm volatile("s_waitcnt vmcnt(4)" ::: "memory");   // tile it landed; it+1 in flight
        } else {
            asm volatile("s_waitcnt vmcnt(0)" ::: "memory");
        }
        __builtin_amdgcn_sched_barrier(0);
        __builtin_amdgcn_s_barrier();
        __builtin_amdgcn_sched_barrier(0);

        const unsigned short* Kl = &Klds[cur][0][0];
        const unsigned short* Vl = &Vlds[cur][0][0];

        // ---- S^T = K Q^T from LDS (swizzled reads) ----
        f32x4 st[2][2] = {};                 // [ni=kv frag][mi=q frag]
        #pragma unroll
        for (int kd = 0; kd < 4; kd++) {
            int swb = ((((kd << 2) | g) ^ (r16 & 7)) << 3);
            short8 kf0 = *reinterpret_cast<const short8*>(Kl + r16 * 128 + swb);
            short8 kf1 = *reinterpret_cast<const short8*>(Kl + (16 + r16) * 128 + swb);
            __builtin_amdgcn_s_setprio(1);
            st[0][0] = __builtin_amdgcn_mfma_f32_16x16x32_bf16(kf0, qf[0][kd], st[0][0], 0, 0, 0);
            st[0][1] = __builtin_amdgcn_mfma_f32_16x16x32_bf16(kf0, qf[1][kd], st[0][1], 0, 0, 0);
            st[1][0] = __builtin_amdgcn_mfma_f32_16x16x32_bf16(kf1, qf[0][kd], st[1][0], 0, 0, 0);
            st[1][1] = __builtin_amdgcn_mfma_f32_16x16x32_bf16(kf1, qf[1][kd], st[1][1], 0, 0, 0);
            __builtin_amdgcn_s_setprio(0);
        }

        // ---- online softmax (exp2 domain), per q-column (mi,r16) ----
        const bool anymask = (kvb + 31 > qw);
        float alpha[2];
        #pragma unroll
        for (int mi = 0; mi < 2; mi++) {
            const int qrow = qw + mi * 16 + r16;
            float s[2][4];
            #pragma unroll
            for (int ni = 0; ni < 2; ni++)
                #pragma unroll
                for (int e = 0; e < 4; e++) {
                    float v = st[ni][mi][e] * scale2;
                    if (anymask && (kvb + ni * 16 + g * 4 + e > qrow)) v = -1e30f;
                    s[ni][e] = v;
                }
            float lm = fmaxf(fmaxf(fmaxf(s[0][0], s[0][1]), fmaxf(s[0][2], s[0][3])),
                             fmaxf(fmaxf(s[1][0], s[1][1]), fmaxf(s[1][2], s[1][3])));
            lm = fmaxf(lm, __shfl_xor(lm, 16));
            lm = fmaxf(lm, __shfl_xor(lm, 32));
            float mnew = fmaxf(m_run[mi], lm);
            alpha[mi] = exp2f(m_run[mi] - mnew);
            float ps[2][4], ls;
            #pragma unroll
            for (int ni = 0; ni < 2; ni++)
                #pragma unroll
                for (int e = 0; e < 4; e++)
                    ps[ni][e] = exp2f(s[ni][e] - mnew);
            ls = ((ps[0][0] + ps[0][1]) + (ps[0][2] + ps[0][3]))
               + ((ps[1][0] + ps[1][1]) + (ps[1][2] + ps[1][3]));
            ls += __shfl_xor(ls, 16);
            ls += __shfl_xor(ls, 32);
            l_run[mi] = l_run[mi] * alpha[mi] + ls;
            m_run[mi] = mnew;
            #pragma unroll
            for (int ni = 0; ni < 2; ni++) {
                ushort4 pk;
                pk.x = f2bf(ps[ni][0]); pk.y = f2bf(ps[ni][1]);
                pk.z = f2bf(ps[ni][2]); pk.w = f2bf(ps[ni][3]);
                *reinterpret_cast<ushort4*>(&Pq[wid][mi * 16 + r16][ni * 16 + g * 4]) = pk;
            }
        }
        if (__any(alpha[0] < 1.f) || __any(alpha[1] < 1.f)) {
            #pragma unroll
            for (int mi = 0; mi < 2; mi++)
                #pragma unroll
                for (int df = 0; df < 8; df++)
                    #pragma unroll
                    for (int e = 0; e < 4; e++)
                        o_acc[mi][df][e] *= alpha[mi];
        }
        // P^T B-fragments: col=q=r16, k=kv=g*8+idx (wave-private Pq: no barrier)
        short8 pb0 = *reinterpret_cast<const short8*>(&Pq[wid][r16][g * 8]);
        short8 pb1 = *reinterpret_cast<const short8*>(&Pq[wid][16 + r16][g * 8]);
        // ---- O^T += V^T P^T, V from LDS (swizzled reads) ----
        const int swv = ((g ^ (r16 & 3)) << 3);
        #pragma unroll
        for (int df = 0; df < 8; df++) {
            short8 vf = *reinterpret_cast<const short8*>(Vl + (df * 16 + r16) * 32 + swv);
            __builtin_amdgcn_s_setprio(1);
            o_acc[0][df] = __builtin_amdgcn_mfma_f32_16x16x32_bf16(vf, pb0, o_acc[0][df], 0, 0, 0);
            o_acc[1][df] = __builtin_amdgcn_mfma_f32_16x16x32_bf16(vf, pb1, o_acc[1][df], 0, 0, 0);
            __builtin_amdgcn_s_setprio(0);
        }

        __builtin_amdgcn_sched_barrier(0);
        __builtin_amdgcn_s_barrier();      // all waves done reading buf[cur]
        __builtin_amdgcn_sched_barrier(0);
        cur ^= 1;
    }

    // ---- epilogue: write partial (or final) straight from registers ----
    if (direct) {
        #pragma unroll
        for (int mi = 0; mi < 2; mi++) {
            float inv = 1.0f / l_run[mi];
            #pragma unroll
            for (int df = 0; df < 8; df++) {
                f32x4 r = o_acc[mi][df];
                r[0] *= inv; r[1] *= inv; r[2] *= inv; r[3] *= inv;
                *reinterpret_cast<f32x4*>(
                    &O[(size_t)(qw + mi * 16 + r16) * DK + df * 16 + g * 4]) = r;
            }
        }
    } else {
        size_t pb0i = ((size_t)t * max_chunks + c) * 32;
        #pragma unroll
        for (int mi = 0; mi < 2; mi++) {
            #pragma unroll
            for (int df = 0; df < 8; df++)
                *reinterpret_cast<f32x4*>(
                    &Opart[(pb0i + mi * 16 + r16) * 128 + df * 16 + g * 4]) = o_acc[mi][df];
            if (g == 0) {
                Mpart[pb0i + mi * 16 + r16] = m_run[mi];
                Lpart[pb0i + mi * 16 + r16] = l_run[mi];
            }
        }
    }
}

// ---------------- merge partials across chunks (exp2 domain) ----------------
__global__ __launch_bounds__(256) void attn_merge(
    const float* __restrict__ Opart, const float* __restrict__ Mpart,
    const float* __restrict__ Lpart, float* __restrict__ O,
    int chunk_tiles, int max_chunks)
{
    __shared__ float Ms[32], Ls[32], Fs[16][32];
    const int t = blockIdx.x;
    const int nc = t / chunk_tiles + 1;
    const int tid = threadIdx.x;

    if (tid < 32) {
        float M = -1e30f;
        for (int c = 0; c < nc; c++)
            M = fmaxf(M, Mpart[((size_t)t * max_chunks + c) * 32 + tid]);
        float L = 0.f;
        for (int c = 0; c < nc; c++) {
            size_t pb = ((size_t)t * max_chunks + c) * 32 + tid;
            L += exp2f(Mpart[pb] - M) * Lpart[pb];
        }
        Ms[tid] = M; Ls[tid] = L;
    }
    __syncthreads();
    for (int cc = tid >> 5; cc < nc; cc += 8) {
        int row = tid & 31;
        Fs[cc][row] = exp2f(Mpart[((size_t)t * max_chunks + cc) * 32 + row] - Ms[row]);
    }
    __syncthreads();
    #pragma unroll
    for (int it = 0; it < 4; it++) {
        int idx = tid + it * 256;
        int row = idx >> 5, c4 = idx & 31;
        float4 acc = {0.f, 0.f, 0.f, 0.f};
        for (int c = 0; c < nc; c++) {
            const float4 v = *reinterpret_cast<const float4*>(
                &Opart[(((size_t)t * max_chunks + c) * 32 + row) * 128 + c4 * 4]);
            float f = Fs[c][row];
            acc.x += f * v.x; acc.y += f * v.y; acc.z += f * v.z; acc.w += f * v.w;
        }
        float inv = 1.0f / Ls[row];
        float4 r;
        r.x = acc.x * inv; r.y = acc.y * inv; r.z = acc.z * inv; r.w = acc.w * inv;
        *reinterpret_cast<float4*>(&O[((size_t)t * 32 + row) * DK + c4 * 4]) = r;
    }
}

extern "C" void kernel_launch(void* const* d_in, const int* in_sizes, int n_in,
                              void* d_out, int out_size, void* d_ws, size_t ws_size,
                              hipStream_t stream) {
    const float* X  = (const float*)d_in[0];
    const float* Wq = (const float*)d_in[1];
    const float* bq = (const float*)d_in[2];
    const float* Wk = (const float*)d_in[3];
    const float* bk = (const float*)d_in[4];
    const float* Wv = (const float*)d_in[5];
    const float* bv = (const float*)d_in[6];
    float* O = (float*)d_out;

    unsigned short* Qb = (unsigned short*)d_ws;
    unsigned short* Kb = Qb + (size_t)N_TOK * DK;
    unsigned short* Vt = Kb + (size_t)N_TOK * DK;
    unsigned short* Wt = Vt + (size_t)N_TOK * DK;
    float* Opart = (float*)(Wt + (size_t)3 * DK * D_IN);
    size_t base_bytes = (size_t)((char*)Opart - (char*)d_ws);

    int chunk_tiles = 0, max_chunks = 1, direct = 0;
    const int opts[4] = {16, 32, 64, 128};
    for (int i = 0; i < 4; i++) {
        int ct = opts[i], mc = NT / ct;
        size_t need = base_bytes + (size_t)NT * mc * 32 * (128 + 2) * sizeof(float);
        if (need <= ws_size) { chunk_tiles = ct; max_chunks = mc; break; }
    }
    if (!chunk_tiles) { chunk_tiles = NT; max_chunks = 1; direct = 1; }
    float* Mpart = Opart + (size_t)NT * max_chunks * 32 * 128;
    float* Lpart = Mpart + (size_t)NT * max_chunks * 32;

    wtrans_kernel<<<dim3(32, 3), 256, 0, stream>>>(Wq, Wk, Wv, Wt);
    proj_fused<<<dim3(256), 256, 0, stream>>>(X, Wt, bq, bk, bv, Qb, Kb, Vt);
    int grid_c = direct ? 1 : max_chunks;
    attn_partial<<<dim3(64, grid_c), 256, 0, stream>>>(
        Qb, Kb, Vt, Opart, Mpart, Lpart, O, chunk_tiles, max_chunks, direct);
    if (!direct)
        attn_merge<<<dim3(NT), 256, 0, stream>>>(Opart, Mpart, Lpart, O,
                                                 chunk_tiles, max_chunks);
}